// Round 1
// baseline (3650.727 us; speedup 1.0000x reference)
//
#include <hip/hip_runtime.h>

#define T_SEQ 1024
#define BATCH 64
#define DIN   300
#define DPAD  320
#define HD    256
#define NW    1536   // 2 dirs * 3 gates * 256
#define ROWS  65536  // B*T

typedef _Float16 f16x8 __attribute__((ext_vector_type(8)));
typedef _Float16 h2_t  __attribute__((ext_vector_type(2)));
typedef float    f32x4 __attribute__((ext_vector_type(4)));

__device__ __forceinline__ float dot2f(h2_t a, h2_t b, float c) {
#if __has_builtin(__builtin_amdgcn_fdot2)
    return __builtin_amdgcn_fdot2(a, b, c, false);
#else
    return c + (float)a[0]*(float)b[0] + (float)a[1]*(float)b[1];
#endif
}

__device__ __forceinline__ float sigmoidf_(float x) { return 1.f/(1.f+__expf(-x)); }
__device__ __forceinline__ float tanhf_(float x)    { return 1.f - 2.f/(__expf(2.f*x)+1.f); }

// ---------------- prep: x -> masked padded f16 [ROWS][DPAD] ----------------
__global__ void prep_x(const float* __restrict__ x, const int* __restrict__ len,
                       _Float16* __restrict__ xh) {
    int r = blockIdx.x, k = threadIdx.x;          // r < 65536, k < 320
    int b = r >> 10, t = r & 1023;
    float v = (k < DIN && t < len[b]) ? x[(size_t)r*DIN + k] : 0.f;
    xh[(size_t)r*DPAD + k] = (_Float16)v;
}

// ------------- prep: weights -> f16 (k-padded), concat biases --------------
__global__ void prep_w(const float* __restrict__ wihf, const float* __restrict__ wihb,
                       const float* __restrict__ bihf, const float* __restrict__ bihb,
                       const float* __restrict__ attw,
                       _Float16* __restrict__ wih, _Float16* __restrict__ attwh,
                       float* __restrict__ bih) {
    int bid = blockIdx.x, tid = threadIdx.x;
    if (bid < NW) {
        const float* src = (bid < 768) ? (wihf + (size_t)bid*DIN)
                                       : (wihb + (size_t)(bid-768)*DIN);
        if (tid < DPAD)
            wih[(size_t)bid*DPAD + tid] = (_Float16)((tid < DIN) ? src[tid] : 0.f);
        if (tid == 0)
            bih[bid] = (bid < 768) ? bihf[bid] : bihb[bid-768];
    } else {
        int n = bid - NW;                          // n < 512, tid < 512
        attwh[(size_t)n*512 + tid] = (_Float16)attw[(size_t)n*512 + tid];
    }
}

// ------- GEMM A: gx[ROWS][1536] = xh @ wih^T + bih   (f16 MFMA) ------------
__global__ __launch_bounds__(256) void gemm_gx(const _Float16* __restrict__ xh,
                                               const _Float16* __restrict__ wih,
                                               const float* __restrict__ bih,
                                               _Float16* __restrict__ gx) {
    int m0 = blockIdx.x * 64, n0 = blockIdx.y * 128;
    __shared__ _Float16 As[64][40];
    __shared__ _Float16 Bs[128][40];
    int tid = threadIdx.x;
    int wave = tid >> 6, lane = tid & 63;
    f32x4 acc[8] = {};
    for (int kt = 0; kt < 10; ++kt) {
        int k0 = kt * 32;
        { // stage A (64 rows x 32 k)
            int r = tid >> 2, ko = (tid & 3) * 8;
            *(f16x8*)&As[r][ko] = *(const f16x8*)&xh[(size_t)(m0+r)*DPAD + k0 + ko];
        }
        { // stage B transposed-as-[n][k] (128 rows x 32 k)
            int r = tid >> 1, ko = (tid & 1) * 16;
            *(f16x8*)&Bs[r][ko]   = *(const f16x8*)&wih[(size_t)(n0+r)*DPAD + k0 + ko];
            *(f16x8*)&Bs[r][ko+8] = *(const f16x8*)&wih[(size_t)(n0+r)*DPAD + k0 + ko + 8];
        }
        __syncthreads();
        int kk = (lane >> 4) * 8;
        f16x8 a = *(const f16x8*)&As[wave*16 + (lane & 15)][kk];
#pragma unroll
        for (int nf = 0; nf < 8; ++nf) {
            f16x8 bfr = *(const f16x8*)&Bs[nf*16 + (lane & 15)][kk];
            acc[nf] = __builtin_amdgcn_mfma_f32_16x16x32_f16(a, bfr, acc[nf], 0, 0, 0);
        }
        __syncthreads();
    }
#pragma unroll
    for (int nf = 0; nf < 8; ++nf) {
        int n = n0 + nf*16 + (lane & 15);
        float bv = bih[n];
#pragma unroll
        for (int r = 0; r < 4; ++r) {
            int m = m0 + wave*16 + (lane >> 4)*4 + r;
            gx[(size_t)m*NW + n] = (_Float16)(acc[nf][r] + bv);
        }
    }
}

// ------------------ GRU recurrence: 128 blocks (b, dir) --------------------
__global__ __launch_bounds__(256, 1) void gru_kernel(
        const float* __restrict__ whhf, const float* __restrict__ whhb,
        const float* __restrict__ bhhf, const float* __restrict__ bhhb,
        const _Float16* __restrict__ gx, _Float16* __restrict__ enc) {
    int bid = blockIdx.x;
    int dir = bid & 1, b = bid >> 1;
    int j = threadIdx.x;
    const float* whh = dir ? whhb : whhf;
    const float* bhh = dir ? bhhb : bhhf;

    // register-resident W_hh rows j (r), 256+j (z), 512+j (n), packed f16x2
    h2_t wr[128], wz[128], wn[128];
    {
        const float4* pr = (const float4*)(whh + (size_t)(0*HD + j)*HD);
        const float4* pz = (const float4*)(whh + (size_t)(1*HD + j)*HD + 0) + 0;
        const float4* pn = (const float4*)(whh + (size_t)(2*HD + j)*HD);
        pz = (const float4*)(whh + (size_t)(HD + j)*HD);
#pragma unroll
        for (int k4 = 0; k4 < 64; ++k4) {
            float4 v = pr[k4];
            wr[2*k4]   = h2_t{(_Float16)v.x, (_Float16)v.y};
            wr[2*k4+1] = h2_t{(_Float16)v.z, (_Float16)v.w};
            float4 u = pz[k4];
            wz[2*k4]   = h2_t{(_Float16)u.x, (_Float16)u.y};
            wz[2*k4+1] = h2_t{(_Float16)u.z, (_Float16)u.w};
            float4 w = pn[k4];
            wn[2*k4]   = h2_t{(_Float16)w.x, (_Float16)w.y};
            wn[2*k4+1] = h2_t{(_Float16)w.z, (_Float16)w.w};
        }
    }
    float br = bhh[j], bz = bhh[HD + j], bn = bhh[2*HD + j];

    __shared__ __align__(16) _Float16 hbuf[2][HD];
    hbuf[0][j] = (_Float16)0.f;
    float hprev = 0.f;
    __syncthreads();

    const _Float16* gxbase = gx + (size_t)b*T_SEQ*NW + dir*768 + j;
    int cur = 0;
    for (int s = 0; s < T_SEQ; ++s) {
        int t = dir ? (T_SEQ - 1 - s) : s;
        const _Float16* gp = gxbase + (size_t)t*NW;
        float xr = (float)gp[0], xz = (float)gp[HD], xn = (float)gp[2*HD];

        float hr0 = br, hr1 = 0.f, hz0 = bz, hz1 = 0.f, hn0 = bn, hn1 = 0.f;
#pragma unroll
        for (int k = 0; k < 32; ++k) {
            f16x8 hv = *(const f16x8*)&hbuf[cur][k*8];
            h2_t a0 = {hv[0], hv[1]}, a1 = {hv[2], hv[3]};
            h2_t a2 = {hv[4], hv[5]}, a3 = {hv[6], hv[7]};
            hr0 = dot2f(a0, wr[4*k+0], hr0); hr1 = dot2f(a1, wr[4*k+1], hr1);
            hr0 = dot2f(a2, wr[4*k+2], hr0); hr1 = dot2f(a3, wr[4*k+3], hr1);
            hz0 = dot2f(a0, wz[4*k+0], hz0); hz1 = dot2f(a1, wz[4*k+1], hz1);
            hz0 = dot2f(a2, wz[4*k+2], hz0); hz1 = dot2f(a3, wz[4*k+3], hz1);
            hn0 = dot2f(a0, wn[4*k+0], hn0); hn1 = dot2f(a1, wn[4*k+1], hn1);
            hn0 = dot2f(a2, wn[4*k+2], hn0); hn1 = dot2f(a3, wn[4*k+3], hn1);
        }
        float r = sigmoidf_(xr + hr0 + hr1);
        float z = sigmoidf_(xz + hz0 + hz1);
        float nn = tanhf_(xn + r * (hn0 + hn1));
        float h = (1.f - z) * nn + z * hprev;
        hprev = h;
        enc[((size_t)(b*T_SEQ + t))*512 + dir*HD + j] = (_Float16)h;
        hbuf[cur ^ 1][j] = (_Float16)h;
        __syncthreads();
        cur ^= 1;
    }
}

// ------ GEMM U + fused tanh/ctx epilogue -> logits[ROWS]  (f16 MFMA) -------
__global__ __launch_bounds__(256) void gemm_u(const _Float16* __restrict__ enc,
                                              const _Float16* __restrict__ attwh,
                                              const float* __restrict__ attb,
                                              const float* __restrict__ ctx,
                                              float* __restrict__ logits) {
    int m0 = blockIdx.x * 64;
    __shared__ _Float16 As[64][40];
    __shared__ _Float16 Bs[512][40];
    int tid = threadIdx.x;
    int wave = tid >> 6, lane = tid & 63;
    f32x4 acc[32] = {};
    for (int kt = 0; kt < 16; ++kt) {
        int k0 = kt * 32;
        { // stage A (64 x 32)
            int r = tid >> 2, ko = (tid & 3) * 8;
            *(f16x8*)&As[r][ko] = *(const f16x8*)&enc[(size_t)(m0+r)*512 + k0 + ko];
        }
        { // stage B as [n][k] (512 x 32)
#pragma unroll
            for (int jr = 0; jr < 2; ++jr) {
                int row = tid*2 + jr;
#pragma unroll
                for (int q = 0; q < 4; ++q)
                    *(f16x8*)&Bs[row][q*8] =
                        *(const f16x8*)&attwh[(size_t)row*512 + k0 + q*8];
            }
        }
        __syncthreads();
        int kk = (lane >> 4) * 8;
        f16x8 a = *(const f16x8*)&As[wave*16 + (lane & 15)][kk];
#pragma unroll
        for (int nf = 0; nf < 32; ++nf) {
            f16x8 bfr = *(const f16x8*)&Bs[nf*16 + (lane & 15)][kk];
            acc[nf] = __builtin_amdgcn_mfma_f32_16x16x32_f16(a, bfr, acc[nf], 0, 0, 0);
        }
        __syncthreads();
    }
    // epilogue: tanh(u + b) . ctx, reduce over n
    float rs0 = 0.f, rs1 = 0.f, rs2 = 0.f, rs3 = 0.f;
#pragma unroll
    for (int nf = 0; nf < 32; ++nf) {
        int n = nf*16 + (lane & 15);
        float bv = attb[n], cv = ctx[n];
        rs0 += tanhf_(acc[nf][0] + bv) * cv;
        rs1 += tanhf_(acc[nf][1] + bv) * cv;
        rs2 += tanhf_(acc[nf][2] + bv) * cv;
        rs3 += tanhf_(acc[nf][3] + bv) * cv;
    }
#pragma unroll
    for (int off = 1; off < 16; off <<= 1) {
        rs0 += __shfl_xor(rs0, off);
        rs1 += __shfl_xor(rs1, off);
        rs2 += __shfl_xor(rs2, off);
        rs3 += __shfl_xor(rs3, off);
    }
    if ((lane & 15) == 0) {
        int mb = m0 + wave*16 + (lane >> 4)*4;
        logits[mb + 0] = rs0;
        logits[mb + 1] = rs1;
        logits[mb + 2] = rs2;
        logits[mb + 3] = rs3;
    }
}

// ---------------- masked softmax over T + weighted pooling -----------------
__global__ __launch_bounds__(256) void softmax_pool(const float* __restrict__ logits,
                                                    const _Float16* __restrict__ enc,
                                                    const int* __restrict__ lengths,
                                                    float* __restrict__ out) {
    int b = blockIdx.x, tid = threadIdx.x;
    int len = lengths[b];
    if (len < 1) len = 1;
    if (len > T_SEQ) len = T_SEQ;
    __shared__ float att[T_SEQ];
    __shared__ float red[8];
    const float* lg = logits + (size_t)b*T_SEQ;

    float m = -1e30f;
    for (int t = tid; t < len; t += 256) m = fmaxf(m, lg[t]);
#pragma unroll
    for (int off = 1; off < 64; off <<= 1) m = fmaxf(m, __shfl_xor(m, off));
    if ((tid & 63) == 0) red[tid >> 6] = m;
    __syncthreads();
    m = fmaxf(fmaxf(red[0], red[1]), fmaxf(red[2], red[3]));

    float s = 0.f;
    for (int t = tid; t < len; t += 256) {
        float e = __expf(lg[t] - m);
        att[t] = e;
        s += e;
    }
#pragma unroll
    for (int off = 1; off < 64; off <<= 1) s += __shfl_xor(s, off);
    if ((tid & 63) == 0) red[4 + (tid >> 6)] = s;
    __syncthreads();
    s = red[4] + red[5] + red[6] + red[7];
    float inv = 1.f / s;

    float a0 = 0.f, a1 = 0.f;
    const _Float16* eb = enc + (size_t)b*T_SEQ*512;
    for (int t = 0; t < len; ++t) {
        float w = att[t];
        a0 += w * (float)eb[(size_t)t*512 + tid];
        a1 += w * (float)eb[(size_t)t*512 + 256 + tid];
    }
    out[(size_t)b*512 + tid]       = a0 * inv;
    out[(size_t)b*512 + 256 + tid] = a1 * inv;
}

extern "C" void kernel_launch(void* const* d_in, const int* in_sizes, int n_in,
                              void* d_out, int out_size, void* d_ws, size_t ws_size,
                              hipStream_t stream) {
    const float* x    = (const float*)d_in[0];
    const int*   len  = (const int*)  d_in[1];
    const float* wihf = (const float*)d_in[2];
    const float* whhf = (const float*)d_in[3];
    const float* bihf = (const float*)d_in[4];
    const float* bhhf = (const float*)d_in[5];
    const float* wihb = (const float*)d_in[6];
    const float* whhb = (const float*)d_in[7];
    const float* bihb = (const float*)d_in[8];
    const float* bhhb = (const float*)d_in[9];
    const float* attw = (const float*)d_in[10];
    const float* attb = (const float*)d_in[11];
    const float* ctxv = (const float*)d_in[12];
    float* out = (float*)d_out;

    char* ws = (char*)d_ws;
    size_t off = 0;
    _Float16* xh    = (_Float16*)(ws + off); off += (size_t)ROWS*DPAD*2;
    _Float16* wih   = (_Float16*)(ws + off); off += (size_t)NW*DPAD*2;
    _Float16* attwh = (_Float16*)(ws + off); off += (size_t)512*512*2;
    float*    bih   = (float*)   (ws + off); off += (size_t)NW*4;
    _Float16* gx    = (_Float16*)(ws + off); off += (size_t)ROWS*NW*2;
    _Float16* enc   = (_Float16*)(ws + off); off += (size_t)ROWS*512*2;
    float*    logit = (float*)   (ws + off); off += (size_t)ROWS*4;

    prep_x<<<dim3(ROWS), dim3(DPAD), 0, stream>>>(x, len, xh);
    prep_w<<<dim3(NW + 512), dim3(512), 0, stream>>>(wihf, wihb, bihf, bihb, attw,
                                                     wih, attwh, bih);
    gemm_gx<<<dim3(ROWS/64, NW/128), dim3(256), 0, stream>>>(xh, wih, bih, gx);
    gru_kernel<<<dim3(2*BATCH), dim3(256), 0, stream>>>(whhf, whhb, bhhf, bhhb, gx, enc);
    gemm_u<<<dim3(ROWS/64), dim3(256), 0, stream>>>(enc, attwh, attb, ctxv, logit);
    softmax_pool<<<dim3(BATCH), dim3(256), 0, stream>>>(logit, enc, len, out);
}

// Round 2
// 1722.531 us; speedup vs baseline: 2.1194x; 2.1194x over previous
//
#include <hip/hip_runtime.h>

#define T_SEQ 1024
#define BATCH 64
#define DIN   300
#define DPAD  320
#define HD    256
#define NW    1536   // 2 dirs * 3 gates * 256
#define ROWS  65536  // B*T

typedef _Float16 f16x8 __attribute__((ext_vector_type(8)));
typedef _Float16 h2_t  __attribute__((ext_vector_type(2)));
typedef float    f32x4 __attribute__((ext_vector_type(4)));

__device__ __forceinline__ float dot2f(h2_t a, h2_t b, float c) {
#if __has_builtin(__builtin_amdgcn_fdot2)
    return __builtin_amdgcn_fdot2(a, b, c, false);
#else
    return c + (float)a[0]*(float)b[0] + (float)a[1]*(float)b[1];
#endif
}

__device__ __forceinline__ float sigmoidf_(float x) { return 1.f/(1.f+__expf(-x)); }
__device__ __forceinline__ float tanhf_(float x)    { return 1.f - 2.f/(__expf(2.f*x)+1.f); }

// ---------------- prep: x -> masked padded f16 [ROWS][DPAD] ----------------
__global__ void prep_x(const float* __restrict__ x, const int* __restrict__ len,
                       _Float16* __restrict__ xh) {
    int r = blockIdx.x, k = threadIdx.x;          // r < 65536, k < 320
    int b = r >> 10, t = r & 1023;
    float v = (k < DIN && t < len[b]) ? x[(size_t)r*DIN + k] : 0.f;
    xh[(size_t)r*DPAD + k] = (_Float16)v;
}

// ------------- prep: weights -> f16 (k-padded), concat biases --------------
__global__ void prep_w(const float* __restrict__ wihf, const float* __restrict__ wihb,
                       const float* __restrict__ bihf, const float* __restrict__ bihb,
                       const float* __restrict__ attw,
                       _Float16* __restrict__ wih, _Float16* __restrict__ attwh,
                       float* __restrict__ bih) {
    int bid = blockIdx.x, tid = threadIdx.x;
    if (bid < NW) {
        const float* src = (bid < 768) ? (wihf + (size_t)bid*DIN)
                                       : (wihb + (size_t)(bid-768)*DIN);
        if (tid < DPAD)
            wih[(size_t)bid*DPAD + tid] = (_Float16)((tid < DIN) ? src[tid] : 0.f);
        if (tid == 0)
            bih[bid] = (bid < 768) ? bihf[bid] : bihb[bid-768];
    } else {
        int n = bid - NW;                          // n < 512, tid < 512
        attwh[(size_t)n*512 + tid] = (_Float16)attw[(size_t)n*512 + tid];
    }
}

// ------- GEMM A: gx[ROWS][1536] = xh @ wih^T + bih   (f16 MFMA) ------------
__global__ __launch_bounds__(256) void gemm_gx(const _Float16* __restrict__ xh,
                                               const _Float16* __restrict__ wih,
                                               const float* __restrict__ bih,
                                               _Float16* __restrict__ gx) {
    int m0 = blockIdx.x * 64, n0 = blockIdx.y * 128;
    __shared__ _Float16 As[64][40];
    __shared__ _Float16 Bs[128][40];
    int tid = threadIdx.x;
    int wave = tid >> 6, lane = tid & 63;
    f32x4 acc[8] = {};
    for (int kt = 0; kt < 10; ++kt) {
        int k0 = kt * 32;
        { // stage A (64 rows x 32 k)
            int r = tid >> 2, ko = (tid & 3) * 8;
            *(f16x8*)&As[r][ko] = *(const f16x8*)&xh[(size_t)(m0+r)*DPAD + k0 + ko];
        }
        { // stage B transposed-as-[n][k] (128 rows x 32 k)
            int r = tid >> 1, ko = (tid & 1) * 16;
            *(f16x8*)&Bs[r][ko]   = *(const f16x8*)&wih[(size_t)(n0+r)*DPAD + k0 + ko];
            *(f16x8*)&Bs[r][ko+8] = *(const f16x8*)&wih[(size_t)(n0+r)*DPAD + k0 + ko + 8];
        }
        __syncthreads();
        int kk = (lane >> 4) * 8;
        f16x8 a = *(const f16x8*)&As[wave*16 + (lane & 15)][kk];
#pragma unroll
        for (int nf = 0; nf < 8; ++nf) {
            f16x8 bfr = *(const f16x8*)&Bs[nf*16 + (lane & 15)][kk];
            acc[nf] = __builtin_amdgcn_mfma_f32_16x16x32_f16(a, bfr, acc[nf], 0, 0, 0);
        }
        __syncthreads();
    }
#pragma unroll
    for (int nf = 0; nf < 8; ++nf) {
        int n = n0 + nf*16 + (lane & 15);
        float bv = bih[n];
#pragma unroll
        for (int r = 0; r < 4; ++r) {
            int m = m0 + wave*16 + (lane >> 4)*4 + r;
            gx[(size_t)m*NW + n] = (_Float16)(acc[nf][r] + bv);
        }
    }
}

// ------------------ GRU recurrence: 128 blocks (b, dir) --------------------
// 512 threads: j = tid>>1 (output idx), half = tid&1 (K-half).
// Each thread holds 3 gates x 64 packed-f16x2 weights = 192 VGPRs (no spill).
// Partial dots combined with one __shfl_xor(.,1); one barrier per step.
__global__ __launch_bounds__(512, 2) void gru_kernel(
        const float* __restrict__ whhf, const float* __restrict__ whhb,
        const float* __restrict__ bhhf, const float* __restrict__ bhhb,
        const _Float16* __restrict__ gx, _Float16* __restrict__ enc) {
    int bid = blockIdx.x;
    int dir = bid & 1, b = bid >> 1;
    int tid = threadIdx.x;
    int j = tid >> 1;
    int half = tid & 1;
    const float* whh = dir ? whhb : whhf;
    const float* bhh = dir ? bhhb : bhhf;

    // weight rows j (r), 256+j (z), 512+j (n); k in [half*128, half*128+128)
    h2_t wr[64], wz[64], wn[64];
    {
        const float2* pr = (const float2*)(whh + (size_t)j*HD        + half*128);
        const float2* pz = (const float2*)(whh + (size_t)(HD + j)*HD + half*128);
        const float2* pn = (const float2*)(whh + (size_t)(2*HD+j)*HD + half*128);
#pragma unroll
        for (int k2 = 0; k2 < 64; ++k2) {
            float2 a = pr[k2]; wr[k2] = h2_t{(_Float16)a.x, (_Float16)a.y};
            float2 c = pz[k2]; wz[k2] = h2_t{(_Float16)c.x, (_Float16)c.y};
            float2 d = pn[k2]; wn[k2] = h2_t{(_Float16)d.x, (_Float16)d.y};
        }
    }
    // bias folded into half==0 accumulator init
    float brh = half ? 0.f : bhh[j];
    float bzh = half ? 0.f : bhh[HD + j];
    float bnh = half ? 0.f : bhh[2*HD + j];

    __shared__ __align__(16) _Float16 hbuf[2][HD];
    if (tid < HD) hbuf[0][tid] = (_Float16)0.f;
    float hprev = 0.f;
    __syncthreads();

    const _Float16* gxb = gx + (size_t)b*T_SEQ*NW + dir*768 + j;
    int t = dir ? (T_SEQ - 1) : 0;
    int dt = dir ? -1 : 1;
    // preload first step's gx
    const _Float16* gp0 = gxb + (size_t)t*NW;
    float xr = (float)gp0[0], xz = (float)gp0[HD], xn = (float)gp0[2*HD];
    int cur = 0;

    for (int s = 0; s < T_SEQ; ++s) {
        // issue next step's gx loads early; waitcnt lands after the dot loop
        float nxr = 0.f, nxz = 0.f, nxn = 0.f;
        if (s + 1 < T_SEQ) {
            const _Float16* gq = gxb + (size_t)(t + dt)*NW;
            nxr = (float)gq[0]; nxz = (float)gq[HD]; nxn = (float)gq[2*HD];
        }

        float hr0 = brh, hz0 = bzh, hn0 = bnh;
        float hr1 = 0.f, hz1 = 0.f, hn1 = 0.f;
        const _Float16* hb = &hbuf[cur][half*128];
#pragma unroll
        for (int k = 0; k < 16; ++k) {
            f16x8 hv = *(const f16x8*)&hb[k*8];
            h2_t a0 = {hv[0], hv[1]}, a1 = {hv[2], hv[3]};
            h2_t a2 = {hv[4], hv[5]}, a3 = {hv[6], hv[7]};
            hr0 = dot2f(a0, wr[4*k+0], hr0); hr1 = dot2f(a1, wr[4*k+1], hr1);
            hr0 = dot2f(a2, wr[4*k+2], hr0); hr1 = dot2f(a3, wr[4*k+3], hr1);
            hz0 = dot2f(a0, wz[4*k+0], hz0); hz1 = dot2f(a1, wz[4*k+1], hz1);
            hz0 = dot2f(a2, wz[4*k+2], hz0); hz1 = dot2f(a3, wz[4*k+3], hz1);
            hn0 = dot2f(a0, wn[4*k+0], hn0); hn1 = dot2f(a1, wn[4*k+1], hn1);
            hn0 = dot2f(a2, wn[4*k+2], hn0); hn1 = dot2f(a3, wn[4*k+3], hn1);
        }
        float hr = hr0 + hr1, hz = hz0 + hz1, hn = hn0 + hn1;
        // combine the two K-halves (pair lanes 2j, 2j+1 — same wave)
        hr += __shfl_xor(hr, 1);
        hz += __shfl_xor(hz, 1);
        hn += __shfl_xor(hn, 1);

        float r  = sigmoidf_(xr + hr);
        float z  = sigmoidf_(xz + hz);
        float nn = tanhf_(xn + r * hn);
        float h  = (1.f - z) * nn + z * hprev;
        hprev = h;
        if (!half) {
            enc[((size_t)(b*T_SEQ + t))*512 + dir*HD + j] = (_Float16)h;
            hbuf[cur ^ 1][j] = (_Float16)h;
        }
        __syncthreads();
        xr = nxr; xz = nxz; xn = nxn;
        cur ^= 1; t += dt;
    }
}

// ------ GEMM U + fused tanh/ctx epilogue -> logits[ROWS]  (f16 MFMA) -------
__global__ __launch_bounds__(256) void gemm_u(const _Float16* __restrict__ enc,
                                              const _Float16* __restrict__ attwh,
                                              const float* __restrict__ attb,
                                              const float* __restrict__ ctx,
                                              float* __restrict__ logits) {
    int m0 = blockIdx.x * 64;
    __shared__ _Float16 As[64][40];
    __shared__ _Float16 Bs[512][40];
    int tid = threadIdx.x;
    int wave = tid >> 6, lane = tid & 63;
    f32x4 acc[32] = {};
    for (int kt = 0; kt < 16; ++kt) {
        int k0 = kt * 32;
        { // stage A (64 x 32)
            int r = tid >> 2, ko = (tid & 3) * 8;
            *(f16x8*)&As[r][ko] = *(const f16x8*)&enc[(size_t)(m0+r)*512 + k0 + ko];
        }
        { // stage B as [n][k] (512 x 32)
#pragma unroll
            for (int jr = 0; jr < 2; ++jr) {
                int row = tid*2 + jr;
#pragma unroll
                for (int q = 0; q < 4; ++q)
                    *(f16x8*)&Bs[row][q*8] =
                        *(const f16x8*)&attwh[(size_t)row*512 + k0 + q*8];
            }
        }
        __syncthreads();
        int kk = (lane >> 4) * 8;
        f16x8 a = *(const f16x8*)&As[wave*16 + (lane & 15)][kk];
#pragma unroll
        for (int nf = 0; nf < 32; ++nf) {
            f16x8 bfr = *(const f16x8*)&Bs[nf*16 + (lane & 15)][kk];
            acc[nf] = __builtin_amdgcn_mfma_f32_16x16x32_f16(a, bfr, acc[nf], 0, 0, 0);
        }
        __syncthreads();
    }
    // epilogue: tanh(u + b) . ctx, reduce over n
    float rs0 = 0.f, rs1 = 0.f, rs2 = 0.f, rs3 = 0.f;
#pragma unroll
    for (int nf = 0; nf < 32; ++nf) {
        int n = nf*16 + (lane & 15);
        float bv = attb[n], cv = ctx[n];
        rs0 += tanhf_(acc[nf][0] + bv) * cv;
        rs1 += tanhf_(acc[nf][1] + bv) * cv;
        rs2 += tanhf_(acc[nf][2] + bv) * cv;
        rs3 += tanhf_(acc[nf][3] + bv) * cv;
    }
#pragma unroll
    for (int off = 1; off < 16; off <<= 1) {
        rs0 += __shfl_xor(rs0, off);
        rs1 += __shfl_xor(rs1, off);
        rs2 += __shfl_xor(rs2, off);
        rs3 += __shfl_xor(rs3, off);
    }
    if ((lane & 15) == 0) {
        int mb = m0 + wave*16 + (lane >> 4)*4;
        logits[mb + 0] = rs0;
        logits[mb + 1] = rs1;
        logits[mb + 2] = rs2;
        logits[mb + 3] = rs3;
    }
}

// ---------------- masked softmax over T + weighted pooling -----------------
__global__ __launch_bounds__(256) void softmax_pool(const float* __restrict__ logits,
                                                    const _Float16* __restrict__ enc,
                                                    const int* __restrict__ lengths,
                                                    float* __restrict__ out) {
    int b = blockIdx.x, tid = threadIdx.x;
    int len = lengths[b];
    if (len < 1) len = 1;
    if (len > T_SEQ) len = T_SEQ;
    __shared__ float att[T_SEQ];
    __shared__ float red[8];
    const float* lg = logits + (size_t)b*T_SEQ;

    float m = -1e30f;
    for (int t = tid; t < len; t += 256) m = fmaxf(m, lg[t]);
#pragma unroll
    for (int off = 1; off < 64; off <<= 1) m = fmaxf(m, __shfl_xor(m, off));
    if ((tid & 63) == 0) red[tid >> 6] = m;
    __syncthreads();
    m = fmaxf(fmaxf(red[0], red[1]), fmaxf(red[2], red[3]));

    float s = 0.f;
    for (int t = tid; t < len; t += 256) {
        float e = __expf(lg[t] - m);
        att[t] = e;
        s += e;
    }
#pragma unroll
    for (int off = 1; off < 64; off <<= 1) s += __shfl_xor(s, off);
    if ((tid & 63) == 0) red[4 + (tid >> 6)] = s;
    __syncthreads();
    s = red[4] + red[5] + red[6] + red[7];
    float inv = 1.f / s;

    float a0 = 0.f, a1 = 0.f;
    const _Float16* eb = enc + (size_t)b*T_SEQ*512;
    for (int t = 0; t < len; ++t) {
        float w = att[t];
        a0 += w * (float)eb[(size_t)t*512 + tid];
        a1 += w * (float)eb[(size_t)t*512 + 256 + tid];
    }
    out[(size_t)b*512 + tid]       = a0 * inv;
    out[(size_t)b*512 + 256 + tid] = a1 * inv;
}

extern "C" void kernel_launch(void* const* d_in, const int* in_sizes, int n_in,
                              void* d_out, int out_size, void* d_ws, size_t ws_size,
                              hipStream_t stream) {
    const float* x    = (const float*)d_in[0];
    const int*   len  = (const int*)  d_in[1];
    const float* wihf = (const float*)d_in[2];
    const float* whhf = (const float*)d_in[3];
    const float* bihf = (const float*)d_in[4];
    const float* bhhf = (const float*)d_in[5];
    const float* wihb = (const float*)d_in[6];
    const float* whhb = (const float*)d_in[7];
    const float* bihb = (const float*)d_in[8];
    const float* bhhb = (const float*)d_in[9];
    const float* attw = (const float*)d_in[10];
    const float* attb = (const float*)d_in[11];
    const float* ctxv = (const float*)d_in[12];
    float* out = (float*)d_out;

    char* ws = (char*)d_ws;
    size_t off = 0;
    _Float16* xh    = (_Float16*)(ws + off); off += (size_t)ROWS*DPAD*2;
    _Float16* wih   = (_Float16*)(ws + off); off += (size_t)NW*DPAD*2;
    _Float16* attwh = (_Float16*)(ws + off); off += (size_t)512*512*2;
    float*    bih   = (float*)   (ws + off); off += (size_t)NW*4;
    _Float16* gx    = (_Float16*)(ws + off); off += (size_t)ROWS*NW*2;
    _Float16* enc   = (_Float16*)(ws + off); off += (size_t)ROWS*512*2;
    float*    logit = (float*)   (ws + off); off += (size_t)ROWS*4;

    prep_x<<<dim3(ROWS), dim3(DPAD), 0, stream>>>(x, len, xh);
    prep_w<<<dim3(NW + 512), dim3(512), 0, stream>>>(wihf, wihb, bihf, bihb, attw,
                                                     wih, attwh, bih);
    gemm_gx<<<dim3(ROWS/64, NW/128), dim3(256), 0, stream>>>(xh, wih, bih, gx);
    gru_kernel<<<dim3(2*BATCH), dim3(512), 0, stream>>>(whhf, whhb, bhhf, bhhb, gx, enc);
    gemm_u<<<dim3(ROWS/64), dim3(256), 0, stream>>>(enc, attwh, attb, ctxv, logit);
    softmax_pool<<<dim3(BATCH), dim3(256), 0, stream>>>(logit, enc, len, out);
}

// Round 3
// 1709.247 us; speedup vs baseline: 2.1359x; 1.0078x over previous
//
#include <hip/hip_runtime.h>

#define T_SEQ 1024
#define BATCH 64
#define DIN   300
#define DPAD  320
#define HD    256
#define NW    1536   // 2 dirs * 3 gates * 256
#define ROWS  65536  // B*T

typedef _Float16 f16x8 __attribute__((ext_vector_type(8)));
typedef _Float16 h2_t  __attribute__((ext_vector_type(2)));
typedef float    f32x4 __attribute__((ext_vector_type(4)));

__device__ __forceinline__ float dot2f(h2_t a, h2_t b, float c) {
#if __has_builtin(__builtin_amdgcn_fdot2)
    return __builtin_amdgcn_fdot2(a, b, c, false);
#else
    return c + (float)a[0]*(float)b[0] + (float)a[1]*(float)b[1];
#endif
}

__device__ __forceinline__ float sigmoidf_(float x) { return 1.f/(1.f+__expf(-x)); }
__device__ __forceinline__ float tanhf_(float x)    { return 1.f - 2.f/(__expf(2.f*x)+1.f); }

// ---------------- prep: x -> masked padded f16 [ROWS][DPAD] ----------------
__global__ void prep_x(const float* __restrict__ x, const int* __restrict__ len,
                       _Float16* __restrict__ xh) {
    int r = blockIdx.x, k = threadIdx.x;          // r < 65536, k < 320
    int b = r >> 10, t = r & 1023;
    float v = (k < DIN && t < len[b]) ? x[(size_t)r*DIN + k] : 0.f;
    xh[(size_t)r*DPAD + k] = (_Float16)v;
}

// ------------- prep: weights -> f16 (k-padded), concat biases --------------
__global__ void prep_w(const float* __restrict__ wihf, const float* __restrict__ wihb,
                       const float* __restrict__ bihf, const float* __restrict__ bihb,
                       const float* __restrict__ attw,
                       _Float16* __restrict__ wih, _Float16* __restrict__ attwh,
                       float* __restrict__ bih) {
    int bid = blockIdx.x, tid = threadIdx.x;
    if (bid < NW) {
        const float* src = (bid < 768) ? (wihf + (size_t)bid*DIN)
                                       : (wihb + (size_t)(bid-768)*DIN);
        if (tid < DPAD)
            wih[(size_t)bid*DPAD + tid] = (_Float16)((tid < DIN) ? src[tid] : 0.f);
        if (tid == 0)
            bih[bid] = (bid < 768) ? bihf[bid] : bihb[bid-768];
    } else {
        int n = bid - NW;                          // n < 512, tid < 512
        attwh[(size_t)n*512 + tid] = (_Float16)attw[(size_t)n*512 + tid];
    }
}

// ------- GEMM A: gx[ROWS][1536] = xh @ wih^T + bih   (f16 MFMA) ------------
__global__ __launch_bounds__(256) void gemm_gx(const _Float16* __restrict__ xh,
                                               const _Float16* __restrict__ wih,
                                               const float* __restrict__ bih,
                                               _Float16* __restrict__ gx) {
    int m0 = blockIdx.x * 64, n0 = blockIdx.y * 128;
    __shared__ _Float16 As[64][40];
    __shared__ _Float16 Bs[128][40];
    int tid = threadIdx.x;
    int wave = tid >> 6, lane = tid & 63;
    f32x4 acc[8] = {};
    for (int kt = 0; kt < 10; ++kt) {
        int k0 = kt * 32;
        { // stage A (64 rows x 32 k)
            int r = tid >> 2, ko = (tid & 3) * 8;
            *(f16x8*)&As[r][ko] = *(const f16x8*)&xh[(size_t)(m0+r)*DPAD + k0 + ko];
        }
        { // stage B transposed-as-[n][k] (128 rows x 32 k)
            int r = tid >> 1, ko = (tid & 1) * 16;
            *(f16x8*)&Bs[r][ko]   = *(const f16x8*)&wih[(size_t)(n0+r)*DPAD + k0 + ko];
            *(f16x8*)&Bs[r][ko+8] = *(const f16x8*)&wih[(size_t)(n0+r)*DPAD + k0 + ko + 8];
        }
        __syncthreads();
        int kk = (lane >> 4) * 8;
        f16x8 a = *(const f16x8*)&As[wave*16 + (lane & 15)][kk];
#pragma unroll
        for (int nf = 0; nf < 8; ++nf) {
            f16x8 bfr = *(const f16x8*)&Bs[nf*16 + (lane & 15)][kk];
            acc[nf] = __builtin_amdgcn_mfma_f32_16x16x32_f16(a, bfr, acc[nf], 0, 0, 0);
        }
        __syncthreads();
    }
#pragma unroll
    for (int nf = 0; nf < 8; ++nf) {
        int n = n0 + nf*16 + (lane & 15);
        float bv = bih[n];
#pragma unroll
        for (int r = 0; r < 4; ++r) {
            int m = m0 + wave*16 + (lane >> 4)*4 + r;
            gx[(size_t)m*NW + n] = (_Float16)(acc[nf][r] + bv);
        }
    }
}

// ------------------ GRU recurrence: 128 blocks (b, dir) --------------------
// 512 threads: j = tid>>1, half = tid&1 (K-half). 192 weight VGPRs/thread.
// amdgpu_waves_per_eu(2,2) pins the 2-waves/SIMD config -> 256-VGPR budget
// (launch_bounds(512,2) empirically capped at 128 and spilled the weights).
__global__ void __launch_bounds__(512)
__attribute__((amdgpu_waves_per_eu(2, 2)))
gru_kernel(
        const float* __restrict__ whhf, const float* __restrict__ whhb,
        const float* __restrict__ bhhf, const float* __restrict__ bhhb,
        const _Float16* __restrict__ gx, _Float16* __restrict__ enc) {
    int bid = blockIdx.x;
    int dir = bid & 1, b = bid >> 1;
    int tid = threadIdx.x;
    int j = tid >> 1;
    int half = tid & 1;
    const float* whh = dir ? whhb : whhf;
    const float* bhh = dir ? bhhb : bhhf;

    // weight rows j (r), 256+j (z), 512+j (n); k in [half*128, half*128+128)
    h2_t wr[64], wz[64], wn[64];
    {
        const float2* pr = (const float2*)(whh + (size_t)j*HD        + half*128);
        const float2* pz = (const float2*)(whh + (size_t)(HD + j)*HD + half*128);
        const float2* pn = (const float2*)(whh + (size_t)(2*HD+j)*HD + half*128);
#pragma unroll
        for (int k2 = 0; k2 < 64; ++k2) {
            float2 a = pr[k2]; wr[k2] = h2_t{(_Float16)a.x, (_Float16)a.y};
            float2 c = pz[k2]; wz[k2] = h2_t{(_Float16)c.x, (_Float16)c.y};
            float2 d = pn[k2]; wn[k2] = h2_t{(_Float16)d.x, (_Float16)d.y};
        }
    }
    // bias folded into half==0 accumulator init
    float brh = half ? 0.f : bhh[j];
    float bzh = half ? 0.f : bhh[HD + j];
    float bnh = half ? 0.f : bhh[2*HD + j];

    __shared__ __align__(16) _Float16 hbuf[2][HD];
    if (tid < HD) hbuf[0][tid] = (_Float16)0.f;
    float hprev = 0.f;
    __syncthreads();

    const _Float16* gxb = gx + (size_t)b*T_SEQ*NW + dir*768 + j;
    int t = dir ? (T_SEQ - 1) : 0;
    int dt = dir ? -1 : 1;
    // preload first step's gx
    const _Float16* gp0 = gxb + (size_t)t*NW;
    float xr = (float)gp0[0], xz = (float)gp0[HD], xn = (float)gp0[2*HD];
    int cur = 0;

    for (int s = 0; s < T_SEQ; ++s) {
        // issue next step's gx loads early; waitcnt lands after the dot loop
        float nxr = 0.f, nxz = 0.f, nxn = 0.f;
        if (s + 1 < T_SEQ) {
            const _Float16* gq = gxb + (size_t)(t + dt)*NW;
            nxr = (float)gq[0]; nxz = (float)gq[HD]; nxn = (float)gq[2*HD];
        }

        float hr0 = brh, hz0 = bzh, hn0 = bnh;
        float hr1 = 0.f, hz1 = 0.f, hn1 = 0.f;
        const _Float16* hb = &hbuf[cur][half*128];
#pragma unroll
        for (int k = 0; k < 16; ++k) {
            f16x8 hv = *(const f16x8*)&hb[k*8];
            h2_t a0 = {hv[0], hv[1]}, a1 = {hv[2], hv[3]};
            h2_t a2 = {hv[4], hv[5]}, a3 = {hv[6], hv[7]};
            hr0 = dot2f(a0, wr[4*k+0], hr0); hr1 = dot2f(a1, wr[4*k+1], hr1);
            hr0 = dot2f(a2, wr[4*k+2], hr0); hr1 = dot2f(a3, wr[4*k+3], hr1);
            hz0 = dot2f(a0, wz[4*k+0], hz0); hz1 = dot2f(a1, wz[4*k+1], hz1);
            hz0 = dot2f(a2, wz[4*k+2], hz0); hz1 = dot2f(a3, wz[4*k+3], hz1);
            hn0 = dot2f(a0, wn[4*k+0], hn0); hn1 = dot2f(a1, wn[4*k+1], hn1);
            hn0 = dot2f(a2, wn[4*k+2], hn0); hn1 = dot2f(a3, wn[4*k+3], hn1);
        }
        float hr = hr0 + hr1, hz = hz0 + hz1, hn = hn0 + hn1;
        // combine the two K-halves (pair lanes 2j, 2j+1 — same wave)
        hr += __shfl_xor(hr, 1);
        hz += __shfl_xor(hz, 1);
        hn += __shfl_xor(hn, 1);

        float r  = sigmoidf_(xr + hr);
        float z  = sigmoidf_(xz + hz);
        float nn = tanhf_(xn + r * hn);
        float h  = (1.f - z) * nn + z * hprev;
        hprev = h;
        // packed h write: thread 4m packs {h_{2m}, h_{2m+1}} -> one 4B store,
        // 16 distinct LDS banks per wave (the old per-f16 writes caused
        // sub-dword same-bank conflicts).
        float hnb = __shfl_xor(h, 2);
        if (!half)
            enc[((size_t)(b*T_SEQ + t))*512 + dir*HD + j] = (_Float16)h;
        if ((tid & 3) == 0) {
            h2_t hp = {(_Float16)h, (_Float16)hnb};
            *(h2_t*)&hbuf[cur ^ 1][j] = hp;
        }
        __syncthreads();
        xr = nxr; xz = nxz; xn = nxn;
        cur ^= 1; t += dt;
    }
}

// ------ GEMM U + fused tanh/ctx epilogue -> logits[ROWS]  (f16 MFMA) -------
__global__ __launch_bounds__(256) void gemm_u(const _Float16* __restrict__ enc,
                                              const _Float16* __restrict__ attwh,
                                              const float* __restrict__ attb,
                                              const float* __restrict__ ctx,
                                              float* __restrict__ logits) {
    int m0 = blockIdx.x * 64;
    __shared__ _Float16 As[64][40];
    __shared__ _Float16 Bs[512][40];
    int tid = threadIdx.x;
    int wave = tid >> 6, lane = tid & 63;
    f32x4 acc[32] = {};
    for (int kt = 0; kt < 16; ++kt) {
        int k0 = kt * 32;
        { // stage A (64 x 32)
            int r = tid >> 2, ko = (tid & 3) * 8;
            *(f16x8*)&As[r][ko] = *(const f16x8*)&enc[(size_t)(m0+r)*512 + k0 + ko];
        }
        { // stage B as [n][k] (512 x 32)
#pragma unroll
            for (int jr = 0; jr < 2; ++jr) {
                int row = tid*2 + jr;
#pragma unroll
                for (int q = 0; q < 4; ++q)
                    *(f16x8*)&Bs[row][q*8] =
                        *(const f16x8*)&attwh[(size_t)row*512 + k0 + q*8];
            }
        }
        __syncthreads();
        int kk = (lane >> 4) * 8;
        f16x8 a = *(const f16x8*)&As[wave*16 + (lane & 15)][kk];
#pragma unroll
        for (int nf = 0; nf < 32; ++nf) {
            f16x8 bfr = *(const f16x8*)&Bs[nf*16 + (lane & 15)][kk];
            acc[nf] = __builtin_amdgcn_mfma_f32_16x16x32_f16(a, bfr, acc[nf], 0, 0, 0);
        }
        __syncthreads();
    }
    // epilogue: tanh(u + b) . ctx, reduce over n
    float rs0 = 0.f, rs1 = 0.f, rs2 = 0.f, rs3 = 0.f;
#pragma unroll
    for (int nf = 0; nf < 32; ++nf) {
        int n = nf*16 + (lane & 15);
        float bv = attb[n], cv = ctx[n];
        rs0 += tanhf_(acc[nf][0] + bv) * cv;
        rs1 += tanhf_(acc[nf][1] + bv) * cv;
        rs2 += tanhf_(acc[nf][2] + bv) * cv;
        rs3 += tanhf_(acc[nf][3] + bv) * cv;
    }
#pragma unroll
    for (int off = 1; off < 16; off <<= 1) {
        rs0 += __shfl_xor(rs0, off);
        rs1 += __shfl_xor(rs1, off);
        rs2 += __shfl_xor(rs2, off);
        rs3 += __shfl_xor(rs3, off);
    }
    if ((lane & 15) == 0) {
        int mb = m0 + wave*16 + (lane >> 4)*4;
        logits[mb + 0] = rs0;
        logits[mb + 1] = rs1;
        logits[mb + 2] = rs2;
        logits[mb + 3] = rs3;
    }
}

// ---------------- masked softmax over T + weighted pooling -----------------
__global__ __launch_bounds__(256) void softmax_pool(const float* __restrict__ logits,
                                                    const _Float16* __restrict__ enc,
                                                    const int* __restrict__ lengths,
                                                    float* __restrict__ out) {
    int b = blockIdx.x, tid = threadIdx.x;
    int len = lengths[b];
    if (len < 1) len = 1;
    if (len > T_SEQ) len = T_SEQ;
    __shared__ float att[T_SEQ];
    __shared__ float red[8];
    const float* lg = logits + (size_t)b*T_SEQ;

    float m = -1e30f;
    for (int t = tid; t < len; t += 256) m = fmaxf(m, lg[t]);
#pragma unroll
    for (int off = 1; off < 64; off <<= 1) m = fmaxf(m, __shfl_xor(m, off));
    if ((tid & 63) == 0) red[tid >> 6] = m;
    __syncthreads();
    m = fmaxf(fmaxf(red[0], red[1]), fmaxf(red[2], red[3]));

    float s = 0.f;
    for (int t = tid; t < len; t += 256) {
        float e = __expf(lg[t] - m);
        att[t] = e;
        s += e;
    }
#pragma unroll
    for (int off = 1; off < 64; off <<= 1) s += __shfl_xor(s, off);
    if ((tid & 63) == 0) red[4 + (tid >> 6)] = s;
    __syncthreads();
    s = red[4] + red[5] + red[6] + red[7];
    float inv = 1.f / s;

    float a0 = 0.f, a1 = 0.f;
    const _Float16* eb = enc + (size_t)b*T_SEQ*512;
    for (int t = 0; t < len; ++t) {
        float w = att[t];
        a0 += w * (float)eb[(size_t)t*512 + tid];
        a1 += w * (float)eb[(size_t)t*512 + 256 + tid];
    }
    out[(size_t)b*512 + tid]       = a0 * inv;
    out[(size_t)b*512 + 256 + tid] = a1 * inv;
}

extern "C" void kernel_launch(void* const* d_in, const int* in_sizes, int n_in,
                              void* d_out, int out_size, void* d_ws, size_t ws_size,
                              hipStream_t stream) {
    const float* x    = (const float*)d_in[0];
    const int*   len  = (const int*)  d_in[1];
    const float* wihf = (const float*)d_in[2];
    const float* whhf = (const float*)d_in[3];
    const float* bihf = (const float*)d_in[4];
    const float* bhhf = (const float*)d_in[5];
    const float* wihb = (const float*)d_in[6];
    const float* whhb = (const float*)d_in[7];
    const float* bihb = (const float*)d_in[8];
    const float* bhhb = (const float*)d_in[9];
    const float* attw = (const float*)d_in[10];
    const float* attb = (const float*)d_in[11];
    const float* ctxv = (const float*)d_in[12];
    float* out = (float*)d_out;

    char* ws = (char*)d_ws;
    size_t off = 0;
    _Float16* xh    = (_Float16*)(ws + off); off += (size_t)ROWS*DPAD*2;
    _Float16* wih   = (_Float16*)(ws + off); off += (size_t)NW*DPAD*2;
    _Float16* attwh = (_Float16*)(ws + off); off += (size_t)512*512*2;
    float*    bih   = (float*)   (ws + off); off += (size_t)NW*4;
    _Float16* gx    = (_Float16*)(ws + off); off += (size_t)ROWS*NW*2;
    _Float16* enc   = (_Float16*)(ws + off); off += (size_t)ROWS*512*2;
    float*    logit = (float*)   (ws + off); off += (size_t)ROWS*4;

    prep_x<<<dim3(ROWS), dim3(DPAD), 0, stream>>>(x, len, xh);
    prep_w<<<dim3(NW + 512), dim3(512), 0, stream>>>(wihf, wihb, bihf, bihb, attw,
                                                     wih, attwh, bih);
    gemm_gx<<<dim3(ROWS/64, NW/128), dim3(256), 0, stream>>>(xh, wih, bih, gx);
    gru_kernel<<<dim3(2*BATCH), dim3(512), 0, stream>>>(whhf, whhb, bhhf, bhhb, gx, enc);
    gemm_u<<<dim3(ROWS/64), dim3(256), 0, stream>>>(enc, attwh, attb, ctxv, logit);
    softmax_pool<<<dim3(BATCH), dim3(256), 0, stream>>>(logit, enc, len, out);
}